// Round 5
// baseline (529.783 us; speedup 1.0000x reference)
//
#include <hip/hip_runtime.h>
#include <hip/hip_bf16.h>

typedef unsigned short u16;
typedef unsigned int u32;

#define BATCH 4
#define NHIST 4
#define NPART 1000
#define NTOPK 10
#define NPT (BATCH*NPART)     // 4000 particles total
#define NET (NPT*NTOPK)       // 40000 edges total

typedef __bf16 b8v __attribute__((ext_vector_type(8)));
typedef float  f4v __attribute__((ext_vector_type(4)));

__device__ __forceinline__ float bf2f(u16 b){
    return __uint_as_float(((u32)b) << 16);
}
__device__ __forceinline__ u16 f2bf(float f){
    u32 u = __float_as_uint(f);
    u32 r = u + 0x7FFF + ((u >> 16) & 1);  // RNE
    return (u16)(r >> 16);
}
// dtype-agnostic input read: element i as float, per runtime flag
__device__ __forceinline__ float ldin(const void* p, size_t i, int isf32){
    return isf32 ? ((const float*)p)[i] : bf2f(((const u16*)p)[i]);
}
// async global->LDS 16B (DMA; dest = wave-uniform base + lane*16 by construction)
__device__ __forceinline__ void async16(void* lds, const void* g){
#if __has_builtin(__builtin_amdgcn_global_load_lds)
    __builtin_amdgcn_global_load_lds((const __attribute__((address_space(1))) u32*)g,
                                     (__attribute__((address_space(3))) u32*)lds, 16, 0, 0);
#else
    *(uint4*)lds = *(const uint4*)g;
#endif
}

// ---------------- dtype probe: a_hist is Uniform[0,1) ----------------
__global__ void k_detect(const void* __restrict__ a_hist, int nu16, int* __restrict__ dflag)
{
    __shared__ int s;
    int t = threadIdx.x;
    if (t == 0) s = 0;
    __syncthreads();
    const u16* p = (const u16*)a_hist;
    int bad = 0;
    for (int i = t; i < nu16; i += 256) bad |= (p[i] & 0x8000) ? 1 : 0;
    if (bad) atomicOr(&s, 1);
    __syncthreads();
    if (t == 0) dflag[0] = s;   // 1 => inputs are float32
}

// ---------------- weight pre-swizzle into MFMA B-frag layout, bf16 ----------------
// Layout per 32-k chunk c: [tile t(16)][lane l(64)][j(8)] = W[c*32+(l>>4)*8+j][t*16+(l&15)]
// 8 weights, chunk counts {1,8,1,8,8,24,16,8} (K = {16,256,5,256,256,768,512,256})
__global__ void k_wxform(const void* w0, const void* w1, const void* w2, const void* w3,
                         const void* w4, const void* w5, const void* w6, const void* w7,
                         const int* __restrict__ dflag, u16* __restrict__ dst)
{
    const int nck[8] = {1,8,1,8,8,24,16,8};
    const int Ks[8]  = {16,256,5,256,256,768,512,256};
    const void* srcs[8] = {w0,w1,w2,w3,w4,w5,w6,w7};
    int isf32 = dflag[0];
    int b = blockIdx.x, wi = 0, c = b;
    while (c >= nck[wi]){ c -= nck[wi]; wi++; }
    const void* src = srcs[wi];
    int K = Ks[wi];
    size_t dbase = (size_t)blockIdx.x * 8192;
    int t = threadIdx.x;
    #pragma unroll 4
    for (int i = 0; i < 32; i++){
        int e = i*256 + t;
        int l = (e >> 3) & 63, j = e & 7, tg = e >> 9;
        int k = c*32 + (l >> 4)*8 + j;
        int n = tg*16 + (l & 15);
        float v = (k < K) ? ldin(src, (size_t)k*256 + n, isf32) : 0.f;
        dst[dbase + e] = f2bf(v);
    }
}

// ---------------- prep: a_cur, s_cur (f32), pe_in (bf16, stride 32) ----------------
__global__ void k_prep(const void* __restrict__ a_hist, const void* __restrict__ s_hist,
                       const void* __restrict__ s_delta, const int* __restrict__ dflag,
                       float* __restrict__ a_cur, float* __restrict__ s_cur,
                       u16* __restrict__ pe_in)
{
    int g = blockIdx.x * 256 + threadIdx.x;
    if (g >= NPT) return;
    int isf32 = dflag[0];
    int b = g / NPART, i = g - b * NPART;
    a_cur[g] = ldin(a_hist, (b*NHIST + NHIST-1)*NPART + i, isf32);
    #pragma unroll
    for (int d = 0; d < 3; d++)
        s_cur[g*3 + d] = ldin(s_hist, (size_t)((b*NHIST + NHIST-1)*NPART + i)*3 + d, isf32);
    #pragma unroll
    for (int h = 0; h < NHIST; h++){
        #pragma unroll
        for (int d = 0; d < 3; d++)
            pe_in[g*32 + h*3 + d] = f2bf(ldin(s_delta, (size_t)((b*NHIST + h)*NPART + i)*3 + d, isf32));
        pe_in[g*32 + 12 + h] = f2bf(ldin(a_hist, (b*NHIST + h)*NPART + i, isf32));
    }
    #pragma unroll
    for (int k = 16; k < 32; k++) pe_in[g*32 + k] = 0;
}

// ---------------- topk edge construction: one wave per receiver ----------------
__global__ __launch_bounds__(256) void k_topk(const float* __restrict__ a_cur,
        const float* __restrict__ s_cur,
        int* __restrict__ send, float* __restrict__ flag, u16* __restrict__ re_in)
{
    __shared__ float sx[NPART], sy[NPART], sz[NPART], sa[NPART];
    int b  = blockIdx.x / 250;
    int r0 = (blockIdx.x % 250) * 4;
    int t = threadIdx.x;
    int wid = t >> 6, lane = t & 63;
    for (int j = t; j < NPART; j += 256){
        int g = b*NPART + j;
        sx[j] = s_cur[g*3+0]; sy[j] = s_cur[g*3+1]; sz[j] = s_cur[g*3+2];
        sa[j] = a_cur[g];
    }
    __syncthreads();
    int i = r0 + wid;
    float xi = sx[i], yi = sy[i], zi = sz[i];
    float ai = sa[i];
    bool tool_i = ai > 0.5f;

    float bd[NTOPK]; int bj[NTOPK];
    #pragma unroll
    for (int k = 0; k < NTOPK; k++){ bd[k] = 3.0e38f; bj[k] = 1 << 30; }
    for (int j = lane; j < NPART; j += 64){
        float dx = xi - sx[j], dy = yi - sy[j], dz = zi - sz[j];
        float d = dx*dx + dy*dy + dz*dz;
        if (tool_i && (sa[j] > 0.5f)) d = 1.0e10f;
        if (d < bd[NTOPK-1]){
            float v = d; int vj = j;
            #pragma unroll
            for (int k = 0; k < NTOPK; k++){
                bool sw = v < bd[k];
                float tv = bd[k]; int tj = bj[k];
                if (sw){ bd[k] = v; bj[k] = vj; v = tv; vj = tj; }
            }
        }
    }
    float myd = 0.f; int myj = 0;
    #pragma unroll
    for (int r = 0; r < NTOPK; r++){
        float v = bd[0]; int vj = bj[0];
        #pragma unroll
        for (int s = 32; s > 0; s >>= 1){
            float ov = __shfl_xor(v, s);
            int   oj = __shfl_xor(vj, s);
            if (ov < v || (ov == v && oj < vj)){ v = ov; vj = oj; }
        }
        if (lane == r){ myd = v; myj = vj; }
        bool owner = (bd[0] == v) && (bj[0] == vj);
        if (owner){
            #pragma unroll
            for (int k = 0; k < NTOPK-1; k++){ bd[k] = bd[k+1]; bj[k] = bj[k+1]; }
            bd[NTOPK-1] = 3.0e38f; bj[NTOPK-1] = 1 << 30;
        }
    }
    if (lane < NTOPK){
        int gp = b*NPART + i;
        int re = gp*NTOPK + lane;
        int j = myj;
        float fl = (!tool_i && myd < 0.25f) ? 1.0f : 0.0f;
        send[re] = b*NPART + j;
        flag[re] = fl;
        u16* row = re_in + (size_t)re * 32;
        row[0] = f2bf(fl * ai);
        row[1] = f2bf(fl * sa[j]);
        row[2] = f2bf(fl * (xi - sx[j]));
        row[3] = f2bf(fl * (yi - sy[j]));
        row[4] = f2bf(fl * (zi - sz[j]));
        #pragma unroll
        for (int k = 5; k < 32; k++) row[k] = 0;
    }
}

// ---------------- MFMA GEMM v2: full N=256 per block, async staging ----------------
// Block tile 128x256, 4 waves (2x2), wave tile 64x128 = 4x8 mfma_16x16x32 tiles.
// AMODE: 0=direct(lda), 2=PP concat [A|X1] (K=512), 3=dual small GEMM (blockIdx>>5
//        selects weight bank (+8 chunks) and output bank (+NPT*256); A direct lda=256).
// ACT: 0=linear (no bias), 1=bias+relu, 2=bias+relu+residual. A,res,C bf16.
// A-LDS is XOR-swizzled (16B unit u' = u ^ ((row>>1)&3)) -> 2-way conflicts max (free).
template<int AMODE, int ACT>
__global__ __launch_bounds__(256, 2) void k_mgemm2(
    const u16* __restrict__ A, const u16* __restrict__ X1,
    const u16* __restrict__ Wsw, const void* __restrict__ Wb,
    const int* __restrict__ dflag,
    const u16* __restrict__ res,
    u16* __restrict__ C, int M, int K, int lda)
{
    __shared__ u16 a_lds[128*32];   // 8 KB
    __shared__ u16 w_lds[16*512];   // 16 KB
    int t = threadIdx.x;
    int lane = t & 63, wave = t >> 6;
    int wm = wave >> 1, wn = wave & 1;
    int bid = blockIdx.x;
    if (AMODE == 3){
        int half = bid >> 5; bid &= 31;
        Wsw += (size_t)half * (8*8192);
        C   += (size_t)half * NPT * 256;
    }
    int row0 = bid * 128;

    f4v acc[4][8];
    #pragma unroll
    for (int i = 0; i < 4; i++)
        #pragma unroll
        for (int j = 0; j < 8; j++) acc[i][j] = {0.f,0.f,0.f,0.f};

    int nkc = K >> 5;
    for (int kc = 0; kc < nkc; kc++){
        int kbase = kc * 32;
        // ---- A: 128 rows x 32 k, swizzled slots, async DMA ----
        #pragma unroll
        for (int it = 0; it < 2; it++){
            int e = it*256 + t;             // 0..511 16B-slots
            int row = e >> 2, up = e & 3;
            int q = up ^ ((row >> 1) & 3);  // which global 16B belongs in this slot
            int rg = row0 + row; if (rg >= M) rg = M - 1;
            int kg = kbase + q*8;
            const u16* src;
            if (AMODE == 0 || AMODE == 3){
                src = A + (size_t)rg * lda + kg;
            } else {        // AMODE 2: [A | X1]
                if (kg < 256) src = A  + (size_t)rg * 256 + kg;
                else          src = X1 + (size_t)rg * 256 + (kg - 256);
            }
            async16(&a_lds[e*8], src);
        }
        // ---- W: 16 coltiles x 64 lanes x 8 (contiguous swizzled), async DMA ----
        #pragma unroll
        for (int it = 0; it < 4; it++){
            int e = it*256 + t;             // 0..1023 16B-slots
            async16(&w_lds[e*8], Wsw + (size_t)kc*8192 + (size_t)e*8);
        }
        __syncthreads();                     // drains vmcnt(0) incl. LDS-DMA
        // ---- frags + 32 MFMA ----
        b8v af[4], bfr[8];
        int c4 = lane >> 4;
        #pragma unroll
        for (int i = 0; i < 4; i++){
            int R = wm*64 + i*16 + (lane & 15);
            int up = c4 ^ ((R >> 1) & 3);
            af[i] = *(const b8v*)&a_lds[R*32 + up*8];
        }
        #pragma unroll
        for (int j = 0; j < 8; j++)
            bfr[j] = *(const b8v*)&w_lds[((wn*8 + j)*64 + lane)*8];
        #pragma unroll
        for (int i = 0; i < 4; i++)
            #pragma unroll
            for (int j = 0; j < 8; j++)
                acc[i][j] = __builtin_amdgcn_mfma_f32_16x16x32_bf16(af[i], bfr[j], acc[i][j], 0, 0, 0);
        __syncthreads();
    }
    // ---- epilogue ----
    int isf32 = (ACT >= 1) ? dflag[0] : 0;
    #pragma unroll
    for (int j = 0; j < 8; j++){
        int col = (wn*8 + j)*16 + (lane & 15);
        float bias = (ACT >= 1) ? ldin(Wb, col, isf32) : 0.f;
        #pragma unroll
        for (int i = 0; i < 4; i++){
            int rbase = row0 + wm*64 + i*16 + (lane >> 4)*4;
            #pragma unroll
            for (int r = 0; r < 4; r++){
                int row = rbase + r;
                if (row < M){
                    float v = acc[i][j][r] + bias;
                    if (ACT == 2) v += bf2f(res[(size_t)row*256 + col]);
                    if (ACT >= 1) v = v > 0.f ? v : 0.f;
                    C[(size_t)row*256 + col] = f2bf(v);
                }
            }
        }
    }
}

// ---------------- fused edge assembly + relu + flag-masked aggregation ----------------
// agg[g][c] = sum_k flag[g*10+k] * relu(Erel[e][c] + Pr[g][c] + Ps[send[e]][c] + b[c])
__global__ void k_rpagg(const u16* __restrict__ Erel, const u16* __restrict__ Pr,
                        const u16* __restrict__ Ps, const int* __restrict__ send,
                        const float* __restrict__ flag, const void* __restrict__ rp_b,
                        const int* __restrict__ dflag, u16* __restrict__ agg)
{
    int g = blockIdx.x, c = threadIdx.x;
    int isf32 = dflag[0];
    float bias = ldin(rp_b, c, isf32);
    float pr = bf2f(Pr[(size_t)g*256 + c]);
    float s = 0.f;
    #pragma unroll
    for (int k = 0; k < NTOPK; k++){
        int e = g*NTOPK + k;
        float f = flag[e];                      // block-uniform
        if (f > 0.f){
            float v = bf2f(Erel[(size_t)e*256 + c]) + pr
                    + bf2f(Ps[(size_t)send[e]*256 + c]) + bias;
            s += v > 0.f ? v : 0.f;
        }
    }
    agg[(size_t)g*256 + c] = f2bf(s);
}

// ---------------- final: predh @ pr_w1 + pr_b1 + s_cur -> out ----------------
__global__ void k_final(const u16* __restrict__ ph, const void* __restrict__ w1,
                        const void* __restrict__ b1, const int* __restrict__ dflag,
                        const float* __restrict__ s_cur, void* __restrict__ out)
{
    int idx = blockIdx.x * 256 + threadIdx.x;
    if (idx >= NPT * 3) return;
    int isf32 = dflag[0];
    int g = idx / 3, d = idx - g * 3;
    float s = ldin(b1, d, isf32) + s_cur[idx];
    const u16* row = ph + (size_t)g * 256;
    #pragma unroll 8
    for (int k = 0; k < 256; k++)
        s += bf2f(row[k]) * ldin(w1, k*3 + d, isf32);
    if (isf32) ((float*)out)[idx] = s;
    else       ((u16*)out)[idx]   = f2bf(s);
}

extern "C" void kernel_launch(void* const* d_in, const int* in_sizes, int n_in,
                              void* d_out, int out_size, void* d_ws, size_t ws_size,
                              hipStream_t stream) {
    const void* a_hist = d_in[0];
    const void* s_hist = d_in[1];
    const void* s_delta= d_in[2];
    const void* pe_w0 = d_in[3];  const void* pe_b0 = d_in[4];
    const void* pe_w1 = d_in[5];  const void* pe_b1 = d_in[6];
    const void* re_w0 = d_in[7];  const void* re_b0 = d_in[8];
    const void* re_w1 = d_in[9];  const void* re_b1 = d_in[10];
    const void* re_w2 = d_in[11]; const void* re_b2 = d_in[12];
    const void* rp_w  = d_in[13]; const void* rp_b  = d_in[14];
    const void* pp_w  = d_in[15]; const void* pp_b  = d_in[16];
    const void* pr_w0 = d_in[17]; const void* pr_b0 = d_in[18];
    const void* pr_w1 = d_in[19]; const void* pr_b1 = d_in[20];

    char* base = (char*)d_ws;
    size_t off = 0;
    auto alloc = [&](size_t bytes) -> char* {
        char* p = base + off;
        off += (bytes + 255) & ~(size_t)255;
        return p;
    };
    int*   dflag = (int*)  alloc(16);
    float* a_cur = (float*)alloc(NPT*4);
    float* s_cur = (float*)alloc(NPT*3*4);
    float* flagp = (float*)alloc(NET*4);
    int*   send  = (int*)  alloc(NET*4);
    u16* pe_in = (u16*)alloc((size_t)NPT*32*2);
    u16* re_in = (u16*)alloc((size_t)NET*32*2);
    u16* hp    = (u16*)alloc((size_t)NPT*256*2);
    u16* penc  = (u16*)alloc((size_t)NPT*256*2);
    u16* aggB  = (u16*)alloc((size_t)NPT*256*2);
    u16* peffA = (u16*)alloc((size_t)NPT*256*2);
    u16* peffB = (u16*)alloc((size_t)NPT*256*2);
    u16* predh = (u16*)alloc((size_t)NPT*256*2);
    u16* PrPs  = (u16*)alloc((size_t)2*NPT*256*2);   // Pr | Ps
    u16* E1    = (u16*)alloc((size_t)NET*256*2);     // scratch / relation_encode
    u16* E2    = (u16*)alloc((size_t)NET*256*2);     // scratch / Erel (persistent)
    u16* wsw   = (u16*)alloc((size_t)74*8192*2);

    // swizzled-weight bases (chunks: pe_w0 1, pe_w1 8, re_w0 1, re_w1 8, re_w2 8, rp_w 24, pp_w 16, pr_w0 8)
    u16* sw_pe0 = wsw + (size_t) 0*8192;
    u16* sw_pe1 = wsw + (size_t) 1*8192;
    u16* sw_re0 = wsw + (size_t) 9*8192;
    u16* sw_re1 = wsw + (size_t)10*8192;
    u16* sw_re2 = wsw + (size_t)18*8192;
    u16* sw_rp  = wsw + (size_t)26*8192;   // chunks 0..7 = rp_wA, 8..15 = rp_wB, 16..23 = rp_wC
    u16* sw_pp  = wsw + (size_t)50*8192;
    u16* sw_pr0 = wsw + (size_t)66*8192;

    u16* Pr = PrPs;
    u16* Ps = PrPs + (size_t)NPT*256;

    const int gE = 313;     // ceil(40000/128)
    const int gP = 32;      // ceil(4000/128)

    k_detect<<<1, 256, 0, stream>>>(a_hist, 2000, dflag);
    k_wxform<<<74, 256, 0, stream>>>(pe_w0, pe_w1, re_w0, re_w1, re_w2, rp_w, pp_w, pr_w0, dflag, wsw);
    k_prep<<<(NPT + 255)/256, 256, 0, stream>>>(a_hist, s_hist, s_delta, dflag, a_cur, s_cur, pe_in);
    k_topk<<<1000, 256, 0, stream>>>(a_cur, s_cur, send, flagp, re_in);

    // particle encoder
    k_mgemm2<0,1><<<gP, 256, 0, stream>>>(pe_in, nullptr, sw_pe0, pe_b0, dflag, nullptr, hp,   NPT, 32, 32);
    k_mgemm2<0,1><<<gP, 256, 0, stream>>>(hp,    nullptr, sw_pe1, pe_b1, dflag, nullptr, penc, NPT, 256, 256);

    // relation encoder
    k_mgemm2<0,1><<<gE, 256, 0, stream>>>(re_in, nullptr, sw_re0, re_b0, dflag, nullptr, E1, NET, 32, 32);
    k_mgemm2<0,1><<<gE, 256, 0, stream>>>(E1,    nullptr, sw_re1, re_b1, dflag, nullptr, E2, NET, 256, 256);
    k_mgemm2<0,1><<<gE, 256, 0, stream>>>(E2,    nullptr, sw_re2, re_b2, dflag, nullptr, E1, NET, 256, 256);
    // E1 = relation_encode; Erel = E1 @ rp_wA (step-invariant, linear)
    k_mgemm2<0,0><<<gE, 256, 0, stream>>>(E1, nullptr, sw_rp, nullptr, dflag, nullptr, E2, NET, 256, 256);
    // E2 = Erel (persistent across steps)

    // propagation step 1 (particle_effect = penc)
    k_mgemm2<3,0><<<2*gP, 256, 0, stream>>>(penc, nullptr, sw_rp + (size_t)8*8192, nullptr, dflag, nullptr, PrPs, NPT, 256, 256);
    k_rpagg<<<NPT, 256, 0, stream>>>(E2, Pr, Ps, send, flagp, rp_b, dflag, aggB);
    k_mgemm2<2,2><<<gP, 256, 0, stream>>>(penc, aggB, sw_pp, pp_b, dflag, penc, peffA, NPT, 512, 0);
    // step 2
    k_mgemm2<3,0><<<2*gP, 256, 0, stream>>>(peffA, nullptr, sw_rp + (size_t)8*8192, nullptr, dflag, nullptr, PrPs, NPT, 256, 256);
    k_rpagg<<<NPT, 256, 0, stream>>>(E2, Pr, Ps, send, flagp, rp_b, dflag, aggB);
    k_mgemm2<2,2><<<gP, 256, 0, stream>>>(penc, aggB, sw_pp, pp_b, dflag, peffA, peffB, NPT, 512, 0);
    // step 3
    k_mgemm2<3,0><<<2*gP, 256, 0, stream>>>(peffB, nullptr, sw_rp + (size_t)8*8192, nullptr, dflag, nullptr, PrPs, NPT, 256, 256);
    k_rpagg<<<NPT, 256, 0, stream>>>(E2, Pr, Ps, send, flagp, rp_b, dflag, aggB);
    k_mgemm2<2,2><<<gP, 256, 0, stream>>>(penc, aggB, sw_pp, pp_b, dflag, peffB, peffA, NPT, 512, 0);

    // predictor
    k_mgemm2<0,1><<<gP, 256, 0, stream>>>(peffA, nullptr, sw_pr0, pr_b0, dflag, nullptr, predh, NPT, 256, 256);
    k_final<<<(NPT*3 + 255)/256, 256, 0, stream>>>(predh, pr_w1, pr_b1, dflag, s_cur, (void*)d_out);
}

// Round 6
// 412.147 us; speedup vs baseline: 1.2854x; 1.2854x over previous
//
#include <hip/hip_runtime.h>
#include <hip/hip_bf16.h>

typedef unsigned short u16;
typedef unsigned int u32;

#define BATCH 4
#define NHIST 4
#define NPART 1000
#define NTOPK 10
#define NPT (BATCH*NPART)     // 4000 particles total
#define NET (NPT*NTOPK)       // 40000 edges total

typedef __bf16 b8v __attribute__((ext_vector_type(8)));
typedef float  f4v __attribute__((ext_vector_type(4)));

__device__ __forceinline__ float bf2f(u16 b){
    return __uint_as_float(((u32)b) << 16);
}
__device__ __forceinline__ u16 f2bf(float f){
    u32 u = __float_as_uint(f);
    u32 r = u + 0x7FFF + ((u >> 16) & 1);  // RNE
    return (u16)(r >> 16);
}
// dtype-agnostic input read: element i as float, per runtime flag
__device__ __forceinline__ float ldin(const void* p, size_t i, int isf32){
    return isf32 ? ((const float*)p)[i] : bf2f(((const u16*)p)[i]);
}

// ---------------- dtype probe: a_hist is Uniform[0,1) ----------------
__global__ void k_detect(const void* __restrict__ a_hist, int nu16, int* __restrict__ dflag)
{
    __shared__ int s;
    int t = threadIdx.x;
    if (t == 0) s = 0;
    __syncthreads();
    const u16* p = (const u16*)a_hist;
    int bad = 0;
    for (int i = t; i < nu16; i += 256) bad |= (p[i] & 0x8000) ? 1 : 0;
    if (bad) atomicOr(&s, 1);
    __syncthreads();
    if (t == 0) dflag[0] = s;   // 1 => inputs are float32
}

// ---------------- weight pre-swizzle into MFMA B-frag layout, bf16 ----------------
// Layout per 32-k chunk c: [tile t(16)][lane l(64)][j(8)] = W[c*32+(l>>4)*8+j][t*16+(l&15)]
// 8 weights, chunk counts {1,8,1,8,8,24,16,8} (K = {16,256,5,256,256,768,512,256})
__global__ void k_wxform(const void* w0, const void* w1, const void* w2, const void* w3,
                         const void* w4, const void* w5, const void* w6, const void* w7,
                         const int* __restrict__ dflag, u16* __restrict__ dst)
{
    const int nck[8] = {1,8,1,8,8,24,16,8};
    const int Ks[8]  = {16,256,5,256,256,768,512,256};
    const void* srcs[8] = {w0,w1,w2,w3,w4,w5,w6,w7};
    int isf32 = dflag[0];
    int b = blockIdx.x, wi = 0, c = b;
    while (c >= nck[wi]){ c -= nck[wi]; wi++; }
    const void* src = srcs[wi];
    int K = Ks[wi];
    size_t dbase = (size_t)blockIdx.x * 8192;
    int t = threadIdx.x;
    #pragma unroll 4
    for (int i = 0; i < 32; i++){
        int e = i*256 + t;
        int l = (e >> 3) & 63, j = e & 7, tg = e >> 9;
        int k = c*32 + (l >> 4)*8 + j;
        int n = tg*16 + (l & 15);
        float v = (k < K) ? ldin(src, (size_t)k*256 + n, isf32) : 0.f;
        dst[dbase + e] = f2bf(v);
    }
}

// ---------------- prep: a_cur, s_cur (f32), pe_in (bf16, stride 32) ----------------
__global__ void k_prep(const void* __restrict__ a_hist, const void* __restrict__ s_hist,
                       const void* __restrict__ s_delta, const int* __restrict__ dflag,
                       float* __restrict__ a_cur, float* __restrict__ s_cur,
                       u16* __restrict__ pe_in)
{
    int g = blockIdx.x * 256 + threadIdx.x;
    if (g >= NPT) return;
    int isf32 = dflag[0];
    int b = g / NPART, i = g - b * NPART;
    a_cur[g] = ldin(a_hist, (b*NHIST + NHIST-1)*NPART + i, isf32);
    #pragma unroll
    for (int d = 0; d < 3; d++)
        s_cur[g*3 + d] = ldin(s_hist, (size_t)((b*NHIST + NHIST-1)*NPART + i)*3 + d, isf32);
    #pragma unroll
    for (int h = 0; h < NHIST; h++){
        #pragma unroll
        for (int d = 0; d < 3; d++)
            pe_in[g*32 + h*3 + d] = f2bf(ldin(s_delta, (size_t)((b*NHIST + h)*NPART + i)*3 + d, isf32));
        pe_in[g*32 + 12 + h] = f2bf(ldin(a_hist, (b*NHIST + h)*NPART + i, isf32));
    }
    #pragma unroll
    for (int k = 16; k < 32; k++) pe_in[g*32 + k] = 0;
}

// ---------------- topk edge construction: one wave per receiver ----------------
__global__ __launch_bounds__(256) void k_topk(const float* __restrict__ a_cur,
        const float* __restrict__ s_cur,
        int* __restrict__ send, float* __restrict__ flag, u16* __restrict__ re_in)
{
    __shared__ float sx[NPART], sy[NPART], sz[NPART], sa[NPART];
    int b  = blockIdx.x / 250;
    int r0 = (blockIdx.x % 250) * 4;
    int t = threadIdx.x;
    int wid = t >> 6, lane = t & 63;
    for (int j = t; j < NPART; j += 256){
        int g = b*NPART + j;
        sx[j] = s_cur[g*3+0]; sy[j] = s_cur[g*3+1]; sz[j] = s_cur[g*3+2];
        sa[j] = a_cur[g];
    }
    __syncthreads();
    int i = r0 + wid;
    float xi = sx[i], yi = sy[i], zi = sz[i];
    float ai = sa[i];
    bool tool_i = ai > 0.5f;

    float bd[NTOPK]; int bj[NTOPK];
    #pragma unroll
    for (int k = 0; k < NTOPK; k++){ bd[k] = 3.0e38f; bj[k] = 1 << 30; }
    for (int j = lane; j < NPART; j += 64){
        float dx = xi - sx[j], dy = yi - sy[j], dz = zi - sz[j];
        float d = dx*dx + dy*dy + dz*dz;
        if (tool_i && (sa[j] > 0.5f)) d = 1.0e10f;
        if (d < bd[NTOPK-1]){
            float v = d; int vj = j;
            #pragma unroll
            for (int k = 0; k < NTOPK; k++){
                bool sw = v < bd[k];
                float tv = bd[k]; int tj = bj[k];
                if (sw){ bd[k] = v; bj[k] = vj; v = tv; vj = tj; }
            }
        }
    }
    float myd = 0.f; int myj = 0;
    #pragma unroll
    for (int r = 0; r < NTOPK; r++){
        float v = bd[0]; int vj = bj[0];
        #pragma unroll
        for (int s = 32; s > 0; s >>= 1){
            float ov = __shfl_xor(v, s);
            int   oj = __shfl_xor(vj, s);
            if (ov < v || (ov == v && oj < vj)){ v = ov; vj = oj; }
        }
        if (lane == r){ myd = v; myj = vj; }
        bool owner = (bd[0] == v) && (bj[0] == vj);
        if (owner){
            #pragma unroll
            for (int k = 0; k < NTOPK-1; k++){ bd[k] = bd[k+1]; bj[k] = bj[k+1]; }
            bd[NTOPK-1] = 3.0e38f; bj[NTOPK-1] = 1 << 30;
        }
    }
    if (lane < NTOPK){
        int gp = b*NPART + i;
        int re = gp*NTOPK + lane;
        int j = myj;
        float fl = (!tool_i && myd < 0.25f) ? 1.0f : 0.0f;
        send[re] = b*NPART + j;
        flag[re] = fl;
        u16* row = re_in + (size_t)re * 32;
        row[0] = f2bf(fl * ai);
        row[1] = f2bf(fl * sa[j]);
        row[2] = f2bf(fl * (xi - sx[j]));
        row[3] = f2bf(fl * (yi - sy[j]));
        row[4] = f2bf(fl * (zi - sz[j]));
        #pragma unroll
        for (int k = 5; k < 32; k++) row[k] = 0;
    }
}

// ---------------- MFMA GEMM v3: register-staged (compiler-pipelined), colhalf ----------------
// Block = 4 waves (2x2). TM rows per block; 128 cols per block (colhalf of N=256).
// Wave tile (TM/2) x 64 = (TM/32) x 4 mfma_16x16x32 tiles.
// AMODE: 0=direct(lda), 2=PP concat [A|X1] (K=512), 3=dual bank (PrPs: blockIdx high
//        selects weight bank (+8 chunks) and output bank (+NPT*256); A direct lda=256).
// ACT: 0=linear(no bias), 1=bias+relu, 2=bias+relu+residual.
// A-LDS XOR-swizzled (16B slot up' = up ^ ((row>>1)&3)); staging via registers so the
// compiler hoists next-chunk global loads above the tail barrier (software pipeline).
template<int AMODE, int ACT, int TM>
__global__ __launch_bounds__(256) void k_mgemm3(
    const u16* __restrict__ A, const u16* __restrict__ X1,
    const u16* __restrict__ Wsw, const void* __restrict__ Wb,
    const int* __restrict__ dflag,
    const u16* __restrict__ res,
    u16* __restrict__ C, int M, int K, int lda, int nrb)
{
    __shared__ u16 a_lds[TM*32];    // TM*64 B
    __shared__ u16 w_lds[8*512];    // 8 KB (8 coltiles x 64 lanes x 8)
    int t = threadIdx.x;
    int lane = t & 63, wave = t >> 6;
    int wm = wave >> 1, wn = wave & 1;
    int bid = blockIdx.x;
    if (AMODE == 3){
        int bank = bid / (nrb*2); bid -= bank*(nrb*2);
        Wsw += (size_t)bank * (8*8192);
        C   += (size_t)bank * NPT * 256;
    }
    int rowblk = bid >> 1, ch = bid & 1;
    int row0 = rowblk * TM;
    const int AR = TM/64;           // A 16B-slots per thread

    f4v acc[TM/32][4];
    #pragma unroll
    for (int i = 0; i < TM/32; i++)
        #pragma unroll
        for (int j = 0; j < 4; j++) acc[i][j] = {0.f,0.f,0.f,0.f};

    int nkc = K >> 5;
    for (int kc = 0; kc < nkc; kc++){
        int kbase = kc * 32;
        // ---- global loads into registers (hoistable past tail barrier) ----
        const u16* wsrc = Wsw + (size_t)kc*8192 + ch*4096;
        uint4 rw0 = ((const uint4*)wsrc)[t];
        uint4 rw1 = ((const uint4*)wsrc)[t + 256];
        uint4 ra[AR];
        #pragma unroll
        for (int it = 0; it < AR; it++){
            int e = it*256 + t;             // 16B slot
            int row = e >> 2, up = e & 3;
            int q = up ^ ((row >> 1) & 3);  // XOR swizzle
            int rg = row0 + row; if (rg >= M) rg = M - 1;
            int kg = kbase + q*8;
            const u16* src;
            if (AMODE == 2){
                if (kg < 256) src = A  + (size_t)rg * 256 + kg;
                else          src = X1 + (size_t)rg * 256 + (kg - 256);
            } else {
                src = A + (size_t)rg * lda + kg;
            }
            ra[it] = *(const uint4*)src;
        }
        __syncthreads();                    // prev chunk's frag reads done
        ((uint4*)w_lds)[t] = rw0;
        ((uint4*)w_lds)[t + 256] = rw1;
        #pragma unroll
        for (int it = 0; it < AR; it++)
            ((uint4*)a_lds)[it*256 + t] = ra[it];
        __syncthreads();
        // ---- frags + MFMA ----
        b8v af[TM/32], bfr[4];
        int c4 = lane >> 4;
        #pragma unroll
        for (int i = 0; i < TM/32; i++){
            int R = wm*(TM/2) + i*16 + (lane & 15);
            int up = c4 ^ ((R >> 1) & 3);
            af[i] = *(const b8v*)&a_lds[R*32 + up*8];
        }
        #pragma unroll
        for (int j = 0; j < 4; j++)
            bfr[j] = *(const b8v*)&w_lds[((wn*4 + j)*64 + lane)*8];
        #pragma unroll
        for (int i = 0; i < TM/32; i++)
            #pragma unroll
            for (int j = 0; j < 4; j++)
                acc[i][j] = __builtin_amdgcn_mfma_f32_16x16x32_bf16(af[i], bfr[j], acc[i][j], 0, 0, 0);
    }
    // ---- epilogue ----
    int isf32 = (ACT >= 1) ? dflag[0] : 0;
    #pragma unroll
    for (int j = 0; j < 4; j++){
        int col = ch*128 + (wn*4 + j)*16 + (lane & 15);
        float bias = (ACT >= 1) ? ldin(Wb, col, isf32) : 0.f;
        #pragma unroll
        for (int i = 0; i < TM/32; i++){
            int rbase = row0 + wm*(TM/2) + i*16 + (lane >> 4)*4;
            #pragma unroll
            for (int r = 0; r < 4; r++){
                int row = rbase + r;
                if (row < M){
                    float v = acc[i][j][r] + bias;
                    if (ACT == 2) v += bf2f(res[(size_t)row*256 + col]);
                    if (ACT >= 1) v = v > 0.f ? v : 0.f;
                    C[(size_t)row*256 + col] = f2bf(v);
                }
            }
        }
    }
}

// ---------------- fused edge assembly + relu + flag-masked aggregation ----------------
// agg[g][c] = sum_k flag[g*10+k] * relu(Erel[e][c] + Pr[g][c] + Ps[send[e]][c] + b[c])
__global__ void k_rpagg(const u16* __restrict__ Erel, const u16* __restrict__ Pr,
                        const u16* __restrict__ Ps, const int* __restrict__ send,
                        const float* __restrict__ flag, const void* __restrict__ rp_b,
                        const int* __restrict__ dflag, u16* __restrict__ agg)
{
    int g = blockIdx.x, c = threadIdx.x;
    int isf32 = dflag[0];
    float bias = ldin(rp_b, c, isf32);
    float pr = bf2f(Pr[(size_t)g*256 + c]);
    float s = 0.f;
    #pragma unroll
    for (int k = 0; k < NTOPK; k++){
        int e = g*NTOPK + k;
        float f = flag[e];                      // block-uniform
        if (f > 0.f){
            float v = bf2f(Erel[(size_t)e*256 + c]) + pr
                    + bf2f(Ps[(size_t)send[e]*256 + c]) + bias;
            s += v > 0.f ? v : 0.f;
        }
    }
    agg[(size_t)g*256 + c] = f2bf(s);
}

// ---------------- final: predh @ pr_w1 + pr_b1 + s_cur -> out ----------------
__global__ void k_final(const u16* __restrict__ ph, const void* __restrict__ w1,
                        const void* __restrict__ b1, const int* __restrict__ dflag,
                        const float* __restrict__ s_cur, void* __restrict__ out)
{
    int idx = blockIdx.x * 256 + threadIdx.x;
    if (idx >= NPT * 3) return;
    int isf32 = dflag[0];
    int g = idx / 3, d = idx - g * 3;
    float s = ldin(b1, d, isf32) + s_cur[idx];
    const u16* row = ph + (size_t)g * 256;
    #pragma unroll 8
    for (int k = 0; k < 256; k++)
        s += bf2f(row[k]) * ldin(w1, k*3 + d, isf32);
    if (isf32) ((float*)out)[idx] = s;
    else       ((u16*)out)[idx]   = f2bf(s);
}

extern "C" void kernel_launch(void* const* d_in, const int* in_sizes, int n_in,
                              void* d_out, int out_size, void* d_ws, size_t ws_size,
                              hipStream_t stream) {
    const void* a_hist = d_in[0];
    const void* s_hist = d_in[1];
    const void* s_delta= d_in[2];
    const void* pe_w0 = d_in[3];  const void* pe_b0 = d_in[4];
    const void* pe_w1 = d_in[5];  const void* pe_b1 = d_in[6];
    const void* re_w0 = d_in[7];  const void* re_b0 = d_in[8];
    const void* re_w1 = d_in[9];  const void* re_b1 = d_in[10];
    const void* re_w2 = d_in[11]; const void* re_b2 = d_in[12];
    const void* rp_w  = d_in[13]; const void* rp_b  = d_in[14];
    const void* pp_w  = d_in[15]; const void* pp_b  = d_in[16];
    const void* pr_w0 = d_in[17]; const void* pr_b0 = d_in[18];
    const void* pr_w1 = d_in[19]; const void* pr_b1 = d_in[20];

    char* base = (char*)d_ws;
    size_t off = 0;
    auto alloc = [&](size_t bytes) -> char* {
        char* p = base + off;
        off += (bytes + 255) & ~(size_t)255;
        return p;
    };
    int*   dflag = (int*)  alloc(16);
    float* a_cur = (float*)alloc(NPT*4);
    float* s_cur = (float*)alloc(NPT*3*4);
    float* flagp = (float*)alloc(NET*4);
    int*   send  = (int*)  alloc(NET*4);
    u16* pe_in = (u16*)alloc((size_t)NPT*32*2);
    u16* re_in = (u16*)alloc((size_t)NET*32*2);
    u16* hp    = (u16*)alloc((size_t)NPT*256*2);
    u16* penc  = (u16*)alloc((size_t)NPT*256*2);
    u16* aggB  = (u16*)alloc((size_t)NPT*256*2);
    u16* peffA = (u16*)alloc((size_t)NPT*256*2);
    u16* peffB = (u16*)alloc((size_t)NPT*256*2);
    u16* predh = (u16*)alloc((size_t)NPT*256*2);
    u16* PrPs  = (u16*)alloc((size_t)2*NPT*256*2);   // Pr | Ps
    u16* E1    = (u16*)alloc((size_t)NET*256*2);     // scratch / relation_encode
    u16* E2    = (u16*)alloc((size_t)NET*256*2);     // scratch / Erel (persistent)
    u16* wsw   = (u16*)alloc((size_t)74*8192*2);

    // swizzled-weight bases (chunks: pe_w0 1, pe_w1 8, re_w0 1, re_w1 8, re_w2 8, rp_w 24, pp_w 16, pr_w0 8)
    u16* sw_pe0 = wsw + (size_t) 0*8192;
    u16* sw_pe1 = wsw + (size_t) 1*8192;
    u16* sw_re0 = wsw + (size_t) 9*8192;
    u16* sw_re1 = wsw + (size_t)10*8192;
    u16* sw_re2 = wsw + (size_t)18*8192;
    u16* sw_rp  = wsw + (size_t)26*8192;   // chunks 0..7 = rp_wA(rel), 8..15 = rp_wB(recv), 16..23 = rp_wC(send)
    u16* sw_pp  = wsw + (size_t)50*8192;
    u16* sw_pr0 = wsw + (size_t)66*8192;

    u16* Pr = PrPs;
    u16* Ps = PrPs + (size_t)NPT*256;

    const int nrbE = 313;            // ceil(40000/128)
    const int nrbP = 63;             // ceil(4000/64)
    const int gE = nrbE*2;           // 626 blocks, TM=128
    const int gP = nrbP*2;           // 126 blocks, TM=64

    k_detect<<<1, 256, 0, stream>>>(a_hist, 2000, dflag);
    k_wxform<<<74, 256, 0, stream>>>(pe_w0, pe_w1, re_w0, re_w1, re_w2, rp_w, pp_w, pr_w0, dflag, wsw);
    k_prep<<<(NPT + 255)/256, 256, 0, stream>>>(a_hist, s_hist, s_delta, dflag, a_cur, s_cur, pe_in);
    k_topk<<<1000, 256, 0, stream>>>(a_cur, s_cur, send, flagp, re_in);

    // particle encoder
    k_mgemm3<0,1,64><<<gP, 256, 0, stream>>>(pe_in, nullptr, sw_pe0, pe_b0, dflag, nullptr, hp,   NPT, 32, 32, nrbP);
    k_mgemm3<0,1,64><<<gP, 256, 0, stream>>>(hp,    nullptr, sw_pe1, pe_b1, dflag, nullptr, penc, NPT, 256, 256, nrbP);

    // relation encoder
    k_mgemm3<0,1,128><<<gE, 256, 0, stream>>>(re_in, nullptr, sw_re0, re_b0, dflag, nullptr, E1, NET, 32, 32, nrbE);
    k_mgemm3<0,1,128><<<gE, 256, 0, stream>>>(E1,    nullptr, sw_re1, re_b1, dflag, nullptr, E2, NET, 256, 256, nrbE);
    k_mgemm3<0,1,128><<<gE, 256, 0, stream>>>(E2,    nullptr, sw_re2, re_b2, dflag, nullptr, E1, NET, 256, 256, nrbE);
    // E1 = relation_encode; Erel = E1 @ rp_wA (step-invariant, linear)
    k_mgemm3<0,0,128><<<gE, 256, 0, stream>>>(E1, nullptr, sw_rp, nullptr, dflag, nullptr, E2, NET, 256, 256, nrbE);
    // E2 = Erel (persistent across steps)

    // propagation step 1 (particle_effect = penc)
    k_mgemm3<3,0,64><<<2*gP, 256, 0, stream>>>(penc, nullptr, sw_rp + (size_t)8*8192, nullptr, dflag, nullptr, PrPs, NPT, 256, 256, nrbP);
    k_rpagg<<<NPT, 256, 0, stream>>>(E2, Pr, Ps, send, flagp, rp_b, dflag, aggB);
    k_mgemm3<2,2,64><<<gP, 256, 0, stream>>>(penc, aggB, sw_pp, pp_b, dflag, penc, peffA, NPT, 512, 0, nrbP);
    // step 2
    k_mgemm3<3,0,64><<<2*gP, 256, 0, stream>>>(peffA, nullptr, sw_rp + (size_t)8*8192, nullptr, dflag, nullptr, PrPs, NPT, 256, 256, nrbP);
    k_rpagg<<<NPT, 256, 0, stream>>>(E2, Pr, Ps, send, flagp, rp_b, dflag, aggB);
    k_mgemm3<2,2,64><<<gP, 256, 0, stream>>>(penc, aggB, sw_pp, pp_b, dflag, peffA, peffB, NPT, 512, 0, nrbP);
    // step 3
    k_mgemm3<3,0,64><<<2*gP, 256, 0, stream>>>(peffB, nullptr, sw_rp + (size_t)8*8192, nullptr, dflag, nullptr, PrPs, NPT, 256, 256, nrbP);
    k_rpagg<<<NPT, 256, 0, stream>>>(E2, Pr, Ps, send, flagp, rp_b, dflag, aggB);
    k_mgemm3<2,2,64><<<gP, 256, 0, stream>>>(penc, aggB, sw_pp, pp_b, dflag, peffB, peffA, NPT, 512, 0, nrbP);

    // predictor
    k_mgemm3<0,1,64><<<gP, 256, 0, stream>>>(peffA, nullptr, sw_pr0, pr_b0, dflag, nullptr, predh, NPT, 256, 256, nrbP);
    k_final<<<(NPT*3 + 255)/256, 256, 0, stream>>>(predh, pr_w1, pr_b1, dflag, s_cur, (void*)d_out);
}

// Round 7
// 321.639 us; speedup vs baseline: 1.6471x; 1.2814x over previous
//
#include <hip/hip_runtime.h>
#include <hip/hip_bf16.h>

typedef unsigned short u16;
typedef unsigned int u32;

#define BATCH 4
#define NHIST 4
#define NPART 1000
#define NTOPK 10
#define NPT (BATCH*NPART)     // 4000 particles total
#define NET (NPT*NTOPK)       // 40000 edges total

typedef __bf16 b8v __attribute__((ext_vector_type(8)));
typedef float  f4v __attribute__((ext_vector_type(4)));

__device__ __forceinline__ float bf2f(u16 b){
    return __uint_as_float(((u32)b) << 16);
}
__device__ __forceinline__ u16 f2bf(float f){
    u32 u = __float_as_uint(f);
    u32 r = u + 0x7FFF + ((u >> 16) & 1);  // RNE
    return (u16)(r >> 16);
}
__device__ __forceinline__ float ldin(const void* p, size_t i, int isf32){
    return isf32 ? ((const float*)p)[i] : bf2f(((const u16*)p)[i]);
}

// =============== setup: dtype-probe + weight swizzle + prep + topk (fused) ===============
// grid 1090: blocks 0..73 weight swizzle, 74..89 prep, 90..1089 topk.
// Every block self-detects dtype (a_hist Uniform[0,1): bf16 never sets bit15).
__global__ __launch_bounds__(256) void k_setup(
    const void* __restrict__ a_hist, const void* __restrict__ s_hist,
    const void* __restrict__ s_delta,
    const void* w0, const void* w1, const void* w2, const void* w3,
    const void* w4, const void* w5, const void* w6, const void* w7,
    u16* __restrict__ wsw, int* __restrict__ dflag,
    float* __restrict__ s_cur, u16* __restrict__ pe_in,
    int* __restrict__ send, float* __restrict__ flag, u16* __restrict__ re_in)
{
    __shared__ float sx[NPART], sy[NPART], sz[NPART], sa[NPART];
    __shared__ int sdet;
    int t = threadIdx.x;
    if (t == 0) sdet = 0;
    __syncthreads();
    {
        const u16* p = (const u16*)a_hist;
        int bad = 0;
        for (int i = t; i < 2000; i += 256) bad |= (p[i] >> 15) & 1;
        if (bad) atomicOr(&sdet, 1);
    }
    __syncthreads();
    int isf32 = sdet;
    int bid = blockIdx.x;

    if (bid < 74){
        // ---- weight pre-swizzle into MFMA B-frag layout ----
        // per 32-k chunk c: [tile tg(16)][lane l(64)][j(8)] = W[c*32+(l>>4)*8+j][tg*16+(l&15)]
        const int nck[8] = {1,8,1,8,8,24,16,8};
        const int Ks[8]  = {16,256,5,256,256,768,512,256};
        const void* srcs[8] = {w0,w1,w2,w3,w4,w5,w6,w7};
        int wi = 0, c = bid;
        while (c >= nck[wi]){ c -= nck[wi]; wi++; }
        const void* src = srcs[wi];
        int K = Ks[wi];
        size_t dbase = (size_t)bid * 8192;
        #pragma unroll 4
        for (int i = 0; i < 32; i++){
            int e = i*256 + t;
            int l = (e >> 3) & 63, j = e & 7, tg = e >> 9;
            int k = c*32 + (l >> 4)*8 + j;
            int n = tg*16 + (l & 15);
            float v = (k < K) ? ldin(src, (size_t)k*256 + n, isf32) : 0.f;
            wsw[dbase + e] = f2bf(v);
        }
        return;
    }
    if (bid < 90){
        // ---- prep: s_cur (f32), pe_in (bf16 stride 32) ----
        if (bid == 74 && t == 0) dflag[0] = isf32;
        int g = (bid - 74)*256 + t;
        if (g >= NPT) return;
        int b = g / NPART, i = g - b*NPART;
        #pragma unroll
        for (int d = 0; d < 3; d++)
            s_cur[g*3 + d] = ldin(s_hist, (size_t)((b*NHIST + NHIST-1)*NPART + i)*3 + d, isf32);
        #pragma unroll
        for (int h = 0; h < NHIST; h++){
            #pragma unroll
            for (int d = 0; d < 3; d++)
                pe_in[g*32 + h*3 + d] = f2bf(ldin(s_delta, (size_t)((b*NHIST + h)*NPART + i)*3 + d, isf32));
            pe_in[g*32 + 12 + h] = f2bf(ldin(a_hist, (b*NHIST + h)*NPART + i, isf32));
        }
        #pragma unroll
        for (int k = 16; k < 32; k++) pe_in[g*32 + k] = 0;
        return;
    }
    // ---- topk: one wave per receiver ----
    int tb = bid - 90;
    int b = tb / 250, r0 = (tb % 250) * 4;
    int wid = t >> 6, lane = t & 63;
    for (int j = t; j < NPART; j += 256){
        int ih = (b*NHIST + NHIST-1)*NPART + j;
        sa[j] = ldin(a_hist, ih, isf32);
        sx[j] = ldin(s_hist, (size_t)ih*3 + 0, isf32);
        sy[j] = ldin(s_hist, (size_t)ih*3 + 1, isf32);
        sz[j] = ldin(s_hist, (size_t)ih*3 + 2, isf32);
    }
    __syncthreads();
    int i = r0 + wid;
    float xi = sx[i], yi = sy[i], zi = sz[i];
    float ai = sa[i];
    bool tool_i = ai > 0.5f;

    float bd[NTOPK]; int bj[NTOPK];
    #pragma unroll
    for (int k = 0; k < NTOPK; k++){ bd[k] = 3.0e38f; bj[k] = 1 << 30; }
    for (int j = lane; j < NPART; j += 64){
        float dx = xi - sx[j], dy = yi - sy[j], dz = zi - sz[j];
        float d = dx*dx + dy*dy + dz*dz;
        if (tool_i && (sa[j] > 0.5f)) d = 1.0e10f;
        if (d < bd[NTOPK-1]){
            float v = d; int vj = j;
            #pragma unroll
            for (int k = 0; k < NTOPK; k++){
                bool sw = v < bd[k];
                float tv = bd[k]; int tj = bj[k];
                if (sw){ bd[k] = v; bj[k] = vj; v = tv; vj = tj; }
            }
        }
    }
    float myd = 0.f; int myj = 0;
    #pragma unroll
    for (int r = 0; r < NTOPK; r++){
        float v = bd[0]; int vj = bj[0];
        #pragma unroll
        for (int s = 32; s > 0; s >>= 1){
            float ov = __shfl_xor(v, s);
            int   oj = __shfl_xor(vj, s);
            if (ov < v || (ov == v && oj < vj)){ v = ov; vj = oj; }
        }
        if (lane == r){ myd = v; myj = vj; }
        bool owner = (bd[0] == v) && (bj[0] == vj);
        if (owner){
            #pragma unroll
            for (int k = 0; k < NTOPK-1; k++){ bd[k] = bd[k+1]; bj[k] = bj[k+1]; }
            bd[NTOPK-1] = 3.0e38f; bj[NTOPK-1] = 1 << 30;
        }
    }
    if (lane < NTOPK){
        int gp = b*NPART + i;
        int re = gp*NTOPK + lane;
        int j = myj;
        float fl = (!tool_i && myd < 0.25f) ? 1.0f : 0.0f;
        send[re] = b*NPART + j;
        flag[re] = fl;
        u16* row = re_in + (size_t)re * 32;
        row[0] = f2bf(fl * ai);
        row[1] = f2bf(fl * sa[j]);
        row[2] = f2bf(fl * (xi - sx[j]));
        row[3] = f2bf(fl * (yi - sy[j]));
        row[4] = f2bf(fl * (zi - sz[j]));
        #pragma unroll
        for (int k = 5; k < 32; k++) row[k] = 0;
    }
}

// =============== fused relation chain: re0 -> re1 -> re2 -> Erel (one kernel) ===============
// 626 blocks x 64 edge-rows; full N=256 kept in LDS ping-pong (2 x 32KB = 64KB).
// B-frags read DIRECT from pre-swizzled global weights (L2-resident) - no W LDS.
// Activation LDS layout: 16B unit u' = u ^ (row&31), addr = row*256 + u'*8 + (col&7).
__global__ __launch_bounds__(256) void k_refuse(
    const u16* __restrict__ re_in,
    const u16* __restrict__ W0, const u16* __restrict__ W1,
    const u16* __restrict__ W2, const u16* __restrict__ W3,
    const void* __restrict__ B0, const void* __restrict__ B1,
    const void* __restrict__ B2,
    const int* __restrict__ dflag,
    u16* __restrict__ Eout)
{
    __shared__ u16 H1[64*256];   // 32 KB
    __shared__ u16 H2[64*256];   // 32 KB
    int t = threadIdx.x, lane = t & 63, wave = t >> 6;
    int wm = wave >> 1, wn = wave & 1;
    int row0 = blockIdx.x * 64;
    int isf32 = dflag[0];

    // stage re_in (64 x 32) into H1 (key &3 confines to units 0..3)
    {
        int row = t >> 2, q = t & 3;
        int rg = row0 + row; if (rg >= NET) rg = NET - 1;
        uint4 v = *(const uint4*)(re_in + (size_t)rg*32 + q*8);
        int up = q ^ (row & 3);
        *(uint4*)&H1[row*256 + up*8] = v;
    }
    __syncthreads();

    f4v acc[2][8];
    b8v af[2], bfr[8];

    auto zacc = [&](){
        #pragma unroll
        for (int i = 0; i < 2; i++)
            #pragma unroll
            for (int j = 0; j < 8; j++) acc[i][j] = {0.f,0.f,0.f,0.f};
    };
    auto rdW = [&](const u16* W, int kc){
        #pragma unroll
        for (int j = 0; j < 8; j++)
            bfr[j] = *(const b8v*)(W + (size_t)kc*8192 + ((wn*8 + j)*64 + lane)*8);
    };
    auto rdA = [&](const u16* Hin, int kc){
        #pragma unroll
        for (int i = 0; i < 2; i++){
            int R = wm*32 + i*16 + (lane & 15);
            int u = kc*4 + (lane >> 4);
            int up = u ^ (R & 31);
            af[i] = *(const b8v*)&Hin[R*256 + up*8];
        }
    };
    auto domf = [&](){
        #pragma unroll
        for (int i = 0; i < 2; i++)
            #pragma unroll
            for (int j = 0; j < 8; j++)
                acc[i][j] = __builtin_amdgcn_mfma_f32_16x16x32_bf16(af[i], bfr[j], acc[i][j], 0, 0, 0);
    };
    auto epiLDS = [&](u16* Hout, const void* Wb){
        #pragma unroll
        for (int j = 0; j < 8; j++){
            int col = (wn*8 + j)*16 + (lane & 15);
            float bias = ldin(Wb, col, isf32);
            #pragma unroll
            for (int i = 0; i < 2; i++){
                int rb = wm*32 + i*16 + (lane >> 4)*4;
                #pragma unroll
                for (int r = 0; r < 4; r++){
                    float v = acc[i][j][r] + bias;
                    v = v > 0.f ? v : 0.f;
                    int rr = rb + r;
                    int up = (col >> 3) ^ (rr & 31);
                    Hout[rr*256 + up*8 + (col & 7)] = f2bf(v);
                }
            }
        }
    };

    // L0: H1(K=32, units 0..3 key&3) -> H2
    zacc();
    {
        rdW(W0, 0);
        #pragma unroll
        for (int i = 0; i < 2; i++){
            int R = wm*32 + i*16 + (lane & 15);
            int up = (lane >> 4) ^ (R & 3);
            af[i] = *(const b8v*)&H1[R*256 + up*8];
        }
        domf();
    }
    epiLDS(H2, B0);
    __syncthreads();
    // L1: H2 -> H1
    zacc();
    for (int kc = 0; kc < 8; kc++){ rdW(W1, kc); rdA(H2, kc); domf(); }
    epiLDS(H1, B1);
    __syncthreads();
    // L2: H1 -> H2
    zacc();
    for (int kc = 0; kc < 8; kc++){ rdW(W2, kc); rdA(H1, kc); domf(); }
    epiLDS(H2, B2);
    __syncthreads();
    // L3 (Erel, linear, no bias): H2 -> global
    zacc();
    for (int kc = 0; kc < 8; kc++){ rdW(W3, kc); rdA(H2, kc); domf(); }
    #pragma unroll
    for (int j = 0; j < 8; j++){
        int col = (wn*8 + j)*16 + (lane & 15);
        #pragma unroll
        for (int i = 0; i < 2; i++){
            int rb = row0 + wm*32 + i*16 + (lane >> 4)*4;
            #pragma unroll
            for (int r = 0; r < 4; r++){
                int row = rb + r;
                if (row < NET) Eout[(size_t)row*256 + col] = f2bf(acc[i][j][r]);
            }
        }
    }
}

// =============== fused particle encoder: pe0 -> pe1 (one kernel) ===============
// 125 blocks x 32 rows, full N=256; H (32x256, 16KB) holds layer-0 output.
__global__ __launch_bounds__(256) void k_pefuse(
    const u16* __restrict__ pe_in,
    const u16* __restrict__ W0, const u16* __restrict__ W1,
    const void* __restrict__ B0, const void* __restrict__ B1,
    const int* __restrict__ dflag,
    u16* __restrict__ penc)
{
    __shared__ u16 S[32*32];     // 2 KB input stage
    __shared__ u16 H[32*256];    // 16 KB
    int t = threadIdx.x, lane = t & 63, wave = t >> 6;
    int wm = wave >> 1, wn = wave & 1;
    int row0 = blockIdx.x * 32;
    int isf32 = dflag[0];
    {
        if (t < 128){
            int row = t >> 2, q = t & 3;
            int rg = row0 + row; if (rg >= NPT) rg = NPT - 1;
            uint4 v = *(const uint4*)(pe_in + (size_t)rg*32 + q*8);
            int up = q ^ (row & 3);
            *(uint4*)&S[row*32 + up*8] = v;
        }
    }
    __syncthreads();
    f4v acc[8];
    b8v af, bfr[8];
    // L0: K=32
    #pragma unroll
    for (int j = 0; j < 8; j++) acc[j] = {0.f,0.f,0.f,0.f};
    {
        #pragma unroll
        for (int j = 0; j < 8; j++)
            bfr[j] = *(const b8v*)(W0 + ((wn*8 + j)*64 + lane)*8);
        int R = wm*16 + (lane & 15);
        int up = (lane >> 4) ^ (R & 3);
        af = *(const b8v*)&S[R*32 + up*8];
        #pragma unroll
        for (int j = 0; j < 8; j++)
            acc[j] = __builtin_amdgcn_mfma_f32_16x16x32_bf16(af, bfr[j], acc[j], 0, 0, 0);
    }
    #pragma unroll
    for (int j = 0; j < 8; j++){
        int col = (wn*8 + j)*16 + (lane & 15);
        float bias = ldin(B0, col, isf32);
        int rb = wm*16 + (lane >> 4)*4;
        #pragma unroll
        for (int r = 0; r < 4; r++){
            float v = acc[j][r] + bias;
            v = v > 0.f ? v : 0.f;
            int rr = rb + r;
            int up = (col >> 3) ^ (rr & 31);
            H[rr*256 + up*8 + (col & 7)] = f2bf(v);
        }
    }
    __syncthreads();
    // L1: K=256
    #pragma unroll
    for (int j = 0; j < 8; j++) acc[j] = {0.f,0.f,0.f,0.f};
    for (int kc = 0; kc < 8; kc++){
        #pragma unroll
        for (int j = 0; j < 8; j++)
            bfr[j] = *(const b8v*)(W1 + (size_t)kc*8192 + ((wn*8 + j)*64 + lane)*8);
        int R = wm*16 + (lane & 15);
        int u = kc*4 + (lane >> 4);
        int up = u ^ (R & 31);
        af = *(const b8v*)&H[R*256 + up*8];
        #pragma unroll
        for (int j = 0; j < 8; j++)
            acc[j] = __builtin_amdgcn_mfma_f32_16x16x32_bf16(af, bfr[j], acc[j], 0, 0, 0);
    }
    #pragma unroll
    for (int j = 0; j < 8; j++){
        int col = (wn*8 + j)*16 + (lane & 15);
        float bias = ldin(B1, col, isf32);
        int rb = row0 + wm*16 + (lane >> 4)*4;
        #pragma unroll
        for (int r = 0; r < 4; r++){
            int row = rb + r;
            if (row < NPT){
                float v = acc[j][r] + bias;
                penc[(size_t)row*256 + col] = f2bf(v > 0.f ? v : 0.f);
            }
        }
    }
}

// =============== MFMA GEMM (register-staged, colhalf), particle-sized ===============
// TM rows/block, 128 cols/block. AMODE: 0=direct, 2=PP concat [A|X1], 3=dual-bank PrPs.
// ACT: 0=linear, 2=bias+relu+residual. B-frags direct from global (L2-hot).
template<int AMODE, int ACT, int TM>
__global__ __launch_bounds__(256) void k_mgemm3(
    const u16* __restrict__ A, const u16* __restrict__ X1,
    const u16* __restrict__ Wsw, const void* __restrict__ Wb,
    const int* __restrict__ dflag,
    const u16* __restrict__ res,
    u16* __restrict__ C, int M, int K, int lda, int nrb)
{
    __shared__ u16 a_lds[TM*32];
    int t = threadIdx.x;
    int lane = t & 63, wave = t >> 6;
    int wm = wave >> 1, wn = wave & 1;
    int bid = blockIdx.x;
    if (AMODE == 3){
        int bank = bid / (nrb*2); bid -= bank*(nrb*2);
        Wsw += (size_t)bank * (8*8192);
        C   += (size_t)bank * NPT * 256;
    }
    int rowblk = bid >> 1, ch = bid & 1;
    int row0 = rowblk * TM;
    constexpr int NSLOT = TM*4;

    f4v acc[TM/32][4];
    #pragma unroll
    for (int i = 0; i < TM/32; i++)
        #pragma unroll
        for (int j = 0; j < 4; j++) acc[i][j] = {0.f,0.f,0.f,0.f};

    int nkc = K >> 5;
    for (int kc = 0; kc < nkc; kc++){
        int kbase = kc * 32;
        uint4 ra;
        if (t < NSLOT){
            int row = t >> 2, up = t & 3;
            int q = up ^ ((row >> 1) & 3);
            int rg = row0 + row; if (rg >= M) rg = M - 1;
            int kg = kbase + q*8;
            const u16* src;
            if (AMODE == 2){
                if (kg < 256) src = A  + (size_t)rg * 256 + kg;
                else          src = X1 + (size_t)rg * 256 + (kg - 256);
            } else {
                src = A + (size_t)rg * lda + kg;
            }
            ra = *(const uint4*)src;
        }
        __syncthreads();
        if (t < NSLOT) ((uint4*)a_lds)[t] = ra;
        __syncthreads();
        b8v af[TM/32], bfr[4];
        int c4 = lane >> 4;
        #pragma unroll
        for (int i = 0; i < TM/32; i++){
            int R = wm*(TM/2) + i*16 + (lane & 15);
            int up = c4 ^ ((R >> 1) & 3);
            af[i] = *(const b8v*)&a_lds[R*32 + up*8];
        }
        #pragma unroll
        for (int j = 0; j < 4; j++)
            bfr[j] = *(const b8v*)(Wsw + (size_t)kc*8192 + ch*4096 + ((wn*4 + j)*64 + lane)*8);
        #pragma unroll
        for (int i = 0; i < TM/32; i++)
            #pragma unroll
            for (int j = 0; j < 4; j++)
                acc[i][j] = __builtin_amdgcn_mfma_f32_16x16x32_bf16(af[i], bfr[j], acc[i][j], 0, 0, 0);
    }
    int isf32 = (ACT >= 1) ? dflag[0] : 0;
    #pragma unroll
    for (int j = 0; j < 4; j++){
        int col = ch*128 + (wn*4 + j)*16 + (lane & 15);
        float bias = (ACT >= 1) ? ldin(Wb, col, isf32) : 0.f;
        #pragma unroll
        for (int i = 0; i < TM/32; i++){
            int rbase = row0 + wm*(TM/2) + i*16 + (lane >> 4)*4;
            #pragma unroll
            for (int r = 0; r < 4; r++){
                int row = rbase + r;
                if (row < M){
                    float v = acc[i][j][r] + bias;
                    if (ACT == 2) v += bf2f(res[(size_t)row*256 + col]);
                    if (ACT >= 1) v = v > 0.f ? v : 0.f;
                    C[(size_t)row*256 + col] = f2bf(v);
                }
            }
        }
    }
}

// =============== fused edge assembly + relu + flag-masked aggregation ===============
__global__ void k_rpagg(const u16* __restrict__ Erel, const u16* __restrict__ Pr,
                        const u16* __restrict__ Ps, const int* __restrict__ send,
                        const float* __restrict__ flag, const void* __restrict__ rp_b,
                        const int* __restrict__ dflag, u16* __restrict__ agg)
{
    int g = blockIdx.x, c = threadIdx.x;
    int isf32 = dflag[0];
    float bias = ldin(rp_b, c, isf32);
    float pr = bf2f(Pr[(size_t)g*256 + c]);
    float s = 0.f;
    #pragma unroll
    for (int k = 0; k < NTOPK; k++){
        int e = g*NTOPK + k;
        float f = flag[e];
        if (f > 0.f){
            float v = bf2f(Erel[(size_t)e*256 + c]) + pr
                    + bf2f(Ps[(size_t)send[e]*256 + c]) + bias;
            s += v > 0.f ? v : 0.f;
        }
    }
    agg[(size_t)g*256 + c] = f2bf(s);
}

// =============== fused predictor: GEMM(K=256,relu) + GEMV(256->3) + s_cur ===============
// 125 blocks x 32 rows.
__global__ __launch_bounds__(256) void k_predfuse(
    const u16* __restrict__ peff, const u16* __restrict__ W0,
    const void* __restrict__ B0, const void* __restrict__ w1,
    const void* __restrict__ b1, const int* __restrict__ dflag,
    const float* __restrict__ s_cur, void* __restrict__ out)
{
    __shared__ u16 a_lds[32*32];     // 2 KB chunk stage
    __shared__ u16 H[32*264];        // 16.5 KB padded predh tile
    __shared__ float sw1[768];
    __shared__ float sb1[3];
    int t = threadIdx.x, lane = t & 63, wave = t >> 6;
    int wm = wave >> 1, wn = wave & 1;
    int row0 = blockIdx.x * 32;
    int isf32 = dflag[0];
    #pragma unroll
    for (int i = 0; i < 3; i++) sw1[t + i*256] = ldin(w1, t + i*256, isf32);
    if (t < 3) sb1[t] = ldin(b1, t, isf32);

    f4v acc[8];
    #pragma unroll
    for (int j = 0; j < 8; j++) acc[j] = {0.f,0.f,0.f,0.f};
    for (int kc = 0; kc < 8; kc++){
        uint4 ra;
        if (t < 128){
            int row = t >> 2, up = t & 3;
            int q = up ^ ((row >> 1) & 3);
            int rg = row0 + row;
            ra = *(const uint4*)(peff + (size_t)rg*256 + kc*32 + q*8);
        }
        __syncthreads();
        if (t < 128) ((uint4*)a_lds)[t] = ra;
        __syncthreads();
        b8v af, bfr[8];
        int R = wm*16 + (lane & 15);
        int up = (lane >> 4) ^ ((R >> 1) & 3);
        af = *(const b8v*)&a_lds[R*32 + up*8];
        #pragma unroll
        for (int j = 0; j < 8; j++)
            bfr[j] = *(const b8v*)(W0 + (size_t)kc*8192 + ((wn*8 + j)*64 + lane)*8);
        #pragma unroll
        for (int j = 0; j < 8; j++)
            acc[j] = __builtin_amdgcn_mfma_f32_16x16x32_bf16(af, bfr[j], acc[j], 0, 0, 0);
    }
    #pragma unroll
    for (int j = 0; j < 8; j++){
        int col = (wn*8 + j)*16 + (lane & 15);
        float bias = ldin(B0, col, isf32);
        int rb = wm*16 + (lane >> 4)*4;
        #pragma unroll
        for (int r = 0; r < 4; r++){
            float v = acc[j][r] + bias;
            H[(rb + r)*264 + col] = f2bf(v > 0.f ? v : 0.f);
        }
    }
    __syncthreads();
    // GEMV: thread -> (row, d)
    int row = t >> 3, dd = t & 7;
    if (dd < 3){
        int g = row0 + row;
        float s = sb1[dd] + s_cur[g*3 + dd];
        const u16* hr = &H[row*264];
        #pragma unroll 8
        for (int k = 0; k < 256; k++)
            s += bf2f(hr[k]) * sw1[k*3 + dd];
        if (isf32) ((float*)out)[g*3 + dd] = s;
        else       ((u16*)out)[g*3 + dd]   = f2bf(s);
    }
}

extern "C" void kernel_launch(void* const* d_in, const int* in_sizes, int n_in,
                              void* d_out, int out_size, void* d_ws, size_t ws_size,
                              hipStream_t stream) {
    const void* a_hist = d_in[0];
    const void* s_hist = d_in[1];
    const void* s_delta= d_in[2];
    const void* pe_w0 = d_in[3];  const void* pe_b0 = d_in[4];
    const void* pe_w1 = d_in[5];  const void* pe_b1 = d_in[6];
    const void* re_w0 = d_in[7];  const void* re_b0 = d_in[8];
    const void* re_w1 = d_in[9];  const void* re_b1 = d_in[10];
    const void* re_w2 = d_in[11]; const void* re_b2 = d_in[12];
    const void* rp_w  = d_in[13]; const void* rp_b  = d_in[14];
    const void* pp_w  = d_in[15]; const void* pp_b  = d_in[16];
    const void* pr_w0 = d_in[17]; const void* pr_b0 = d_in[18];
    const void* pr_w1 = d_in[19]; const void* pr_b1 = d_in[20];

    char* base = (char*)d_ws;
    size_t off = 0;
    auto alloc = [&](size_t bytes) -> char* {
        char* p = base + off;
        off += (bytes + 255) & ~(size_t)255;
        return p;
    };
    int*   dflag = (int*)  alloc(16);
    float* s_cur = (float*)alloc(NPT*3*4);
    float* flagp = (float*)alloc(NET*4);
    int*   send  = (int*)  alloc(NET*4);
    u16* pe_in = (u16*)alloc((size_t)NPT*32*2);
    u16* re_in = (u16*)alloc((size_t)NET*32*2);
    u16* penc  = (u16*)alloc((size_t)NPT*256*2);
    u16* aggB  = (u16*)alloc((size_t)NPT*256*2);
    u16* peffA = (u16*)alloc((size_t)NPT*256*2);
    u16* peffB = (u16*)alloc((size_t)NPT*256*2);
    u16* PrPs  = (u16*)alloc((size_t)2*NPT*256*2);
    u16* Erel  = (u16*)alloc((size_t)NET*256*2);
    u16* wsw   = (u16*)alloc((size_t)74*8192*2);

    // swizzled-weight bases (chunks: pe_w0 1, pe_w1 8, re_w0 1, re_w1 8, re_w2 8, rp_w 24, pp_w 16, pr_w0 8)
    u16* sw_pe0 = wsw + (size_t) 0*8192;
    u16* sw_pe1 = wsw + (size_t) 1*8192;
    u16* sw_re0 = wsw + (size_t) 9*8192;
    u16* sw_re1 = wsw + (size_t)10*8192;
    u16* sw_re2 = wsw + (size_t)18*8192;
    u16* sw_rp  = wsw + (size_t)26*8192;   // 0..7 rel | 8..15 recv | 16..23 send
    u16* sw_pp  = wsw + (size_t)50*8192;
    u16* sw_pr0 = wsw + (size_t)66*8192;

    u16* Pr = PrPs;
    u16* Ps = PrPs + (size_t)NPT*256;

    const int nrbP = 125;           // ceil(4000/32)
    const int gP  = nrbP*2;         // 250 (TM=32, colhalf)
    const int gE  = 626;            // ceil(40000/64)

    k_setup<<<1090, 256, 0, stream>>>(a_hist, s_hist, s_delta,
        pe_w0, pe_w1, re_w0, re_w1, re_w2, rp_w, pp_w, pr_w0,
        wsw, dflag, s_cur, pe_in, send, flagp, re_in);

    k_pefuse<<<nrbP, 256, 0, stream>>>(pe_in, sw_pe0, sw_pe1, pe_b0, pe_b1, dflag, penc);

    k_refuse<<<gE, 256, 0, stream>>>(re_in, sw_re0, sw_re1, sw_re2, sw_rp,
                                     re_b0, re_b1, re_b2, dflag, Erel);

    // propagation step 1
    k_mgemm3<3,0,32><<<2*gP, 256, 0, stream>>>(penc, nullptr, sw_rp + (size_t)8*8192, nullptr, dflag, nullptr, PrPs, NPT, 256, 256, nrbP);
    k_rpagg<<<NPT, 256, 0, stream>>>(Erel, Pr, Ps, send, flagp, rp_b, dflag, aggB);
    k_mgemm3<2,2,32><<<gP, 256, 0, stream>>>(penc, aggB, sw_pp, pp_b, dflag, penc, peffA, NPT, 512, 0, nrbP);
    // step 2
    k_mgemm3<3,0,32><<<2*gP, 256, 0, stream>>>(peffA, nullptr, sw_rp + (size_t)8*8192, nullptr, dflag, nullptr, PrPs, NPT, 256, 256, nrbP);
    k_rpagg<<<NPT, 256, 0, stream>>>(Erel, Pr, Ps, send, flagp, rp_b, dflag, aggB);
    k_mgemm3<2,2,32><<<gP, 256, 0, stream>>>(penc, aggB, sw_pp, pp_b, dflag, peffA, peffB, NPT, 512, 0, nrbP);
    // step 3
    k_mgemm3<3,0,32><<<2*gP, 256, 0, stream>>>(peffB, nullptr, sw_rp + (size_t)8*8192, nullptr, dflag, nullptr, PrPs, NPT, 256, 256, nrbP);
    k_rpagg<<<NPT, 256, 0, stream>>>(Erel, Pr, Ps, send, flagp, rp_b, dflag, aggB);
    k_mgemm3<2,2,32><<<gP, 256, 0, stream>>>(penc, aggB, sw_pp, pp_b, dflag, peffB, peffA, NPT, 512, 0, nrbP);

    // fused predictor + output
    k_predfuse<<<nrbP, 256, 0, stream>>>(peffA, sw_pr0, pr_b0, pr_w1, pr_b1, dflag, s_cur, (void*)d_out);
}